// Round 5
// baseline (149.866 us; speedup 1.0000x reference)
//
#include <hip/hip_runtime.h>

// Depthwise 21x21 Gaussian blur, reflect pad 10, 16x3x512x512 fp32.
// Separable: phi[j] = W[ch][10][j] / sqrt(W[ch][10][10]).
// R5 vs R4 (latency-bound diagnosis: all pipes <40%, 5 blocks/CU):
//  - TY 32->16: LDS 31.7KB->23.0KB (45x512B granules) -> 7 blocks/CU, 28 waves.
//  - float4 staging (interior fast path, left halo 12 for 16B alignment) +
//    ds_write_b128; h-pass win = 8x ds_read_b128 (quad-stride 23, odd).
//  - sB row-major: h-writes 2x b128 (quad-stride 17, odd); v-reads are
//    64-consecutive-float wave ops (2-way, free).
//  - sPhi removed (kept LDS under the 7-block edge); taps via uniform
//    global loads -> readfirstlane -> SGPRs.

constexpr int IMG = 512;
constexpr int KS  = 21;
constexpr int RAD = 10;
constexpr int TX  = 64;
constexpr int TY  = 16;
constexpr int HY  = TY + 2 * RAD;   // 36 h-filtered rows needed
constexpr int SAQ = 23;             // sA row stride in float4 (92 floats, quad-stride odd)
constexpr int SBF = 68;             // sB row stride in floats (17 float4, quad-stride odd)

__global__ __launch_bounds__(256, 7) void gauss2d_sep(const float* __restrict__ x,
                                                      const float* __restrict__ W,
                                                      float* __restrict__ out)
{
    __shared__ float4 sA4[HY * SAQ];        // 13248 B, [row][col/4], cols = tx-12 .. tx+75
    __shared__ float4 sB4[HY * (SBF / 4)];  //  9792 B, [row][col] row-major h-output
    float* sA = (float*)sA4;
    float* sB = (float*)sB4;

    const int tid = threadIdx.x;
    const int bx = blockIdx.x, by = blockIdx.y, bc = blockIdx.z;
    const int tx = bx * TX, ty = by * TY;
    const int ch = bc % 3;

    // Separable taps from the 2D weight; wave-uniform -> SGPRs.
    const float* wr = W + ch * (KS * KS) + RAD * KS;
    const float inv = 1.0f / sqrtf(wr[RAD]);
    float ph[KS];
    #pragma unroll
    for (int j = 0; j < KS; ++j)
        ph[j] = __int_as_float(__builtin_amdgcn_readfirstlane(__float_as_int(wr[j] * inv)));

    const float* __restrict__ xin = x + (size_t)bc * (IMG * IMG);

    // ---- Stage HY x 88 input tile (cols tx-12 .. tx+75; need tx-10..tx+73) ----
    const bool interior = (bx >= 1) & (bx <= 6) & (by >= 1) & (by <= 30);
    if (interior) {
        const float4* xin4 = (const float4*)xin;   // (tx-12)*4 B is 16B-aligned
        const int base4 = ((ty - RAD) * IMG + (tx - 12)) >> 2;
        for (int e = tid; e < HY * 22; e += 256) { // 792 f4 tasks, coalesced
            int r = e / 22, q = e - r * 22;
            sA4[r * SAQ + q] = xin4[base4 + r * (IMG / 4) + q];
        }
    } else {
        for (int e = tid; e < HY * 88; e += 256) { // scalar reflect path
            int r = e / 88, c = e - r * 88;
            int gr = ty + r - RAD;
            gr = (gr < 0) ? -gr : gr;  gr = (gr >= IMG) ? 2 * IMG - 2 - gr : gr;
            int gc = tx + c - 12;
            gc = (gc < 0) ? -gc : gc;  gc = (gc >= IMG) ? 2 * IMG - 2 - gc : gc;
            sA[r * (4 * SAQ) + c] = xin[gr * IMG + gc];
        }
    }
    __syncthreads();

    // ---- Horizontal pass: 36 rows x 8 chunks of 8 cols = 288 tasks ----
    // Output col c needs sA cols c+2 .. c+22 (sA col 0 = global tx-12).
    for (int e = tid; e < HY * 8; e += 256) {
        const int r  = e >> 3;
        const int c0 = (e & 7) << 3;
        float4 w4[8];
        #pragma unroll
        for (int k = 0; k < 8; ++k) w4[k] = sA4[r * SAQ + (c0 >> 2) + k];
        float win[32];
        #pragma unroll
        for (int k = 0; k < 8; ++k) {
            win[4 * k]     = w4[k].x;  win[4 * k + 1] = w4[k].y;
            win[4 * k + 2] = w4[k].z;  win[4 * k + 3] = w4[k].w;
        }
        float acc[8];
        #pragma unroll
        for (int i = 0; i < 8; ++i) {
            float a = ph[0] * win[i + 2];
            #pragma unroll
            for (int j = 1; j < KS; ++j) a += ph[j] * win[i + 2 + j];
            acc[i] = a;
        }
        float4 o0 = {acc[0], acc[1], acc[2], acc[3]};
        float4 o1 = {acc[4], acc[5], acc[6], acc[7]};
        sB4[r * (SBF / 4) + (c0 >> 2)]     = o0;   // b128, quad-stride 17 (odd)
        sB4[r * (SBF / 4) + (c0 >> 2) + 1] = o1;
    }
    __syncthreads();

    // ---- Vertical pass: col = tid&63, rows [4g, 4g+4), g = tid>>6 ----
    {
        const int c = tid & 63;
        const int g = tid >> 6;
        float win[24];
        #pragma unroll
        for (int k = 0; k < 24; ++k)
            win[k] = sB[(4 * g + k) * SBF + c];    // wave reads 64 consecutive floats
        float acc[4];
        #pragma unroll
        for (int i = 0; i < 4; ++i) {
            float a = ph[0] * win[i];
            #pragma unroll
            for (int j = 1; j < KS; ++j) a += ph[j] * win[i + j];
            acc[i] = a;
        }
        float* __restrict__ oimg = out + (size_t)bc * (IMG * IMG)
                                 + (size_t)(ty + 4 * g) * IMG + (tx + c);
        #pragma unroll
        for (int i = 0; i < 4; ++i)
            oimg[i * IMG] = acc[i];                // coalesced
    }
}

extern "C" void kernel_launch(void* const* d_in, const int* in_sizes, int n_in,
                              void* d_out, int out_size, void* d_ws, size_t ws_size,
                              hipStream_t stream) {
    const float* x = (const float*)d_in[0];
    const float* W = (const float*)d_in[1];
    float* out     = (float*)d_out;
    dim3 grid(IMG / TX, IMG / TY, 16 * 3);
    gauss2d_sep<<<grid, 256, 0, stream>>>(x, W, out);
}